// Round 6
// baseline (2021.815 us; speedup 1.0000x reference)
//
#include <hip/hip_runtime.h>

#define N_NODES 50000
#define N_EDGES 800000
#define F 64
#define EDIM 16
#define NPB 64                              // dst nodes per block
#define NBLK ((N_NODES + NPB - 1) / NPB)    // 782
#define TPB 256                             // 4 waves
#define NWAVE 4
#define NPW (NPB / NWAVE)                   // 16 nodes per wave (node phase)
#define NEG_SLOPE 0.01f
#define SCAN_B 1024
#define SCAN_NB ((N_NODES + SCAN_B - 1) / SCAN_B)   // 49

// ---------------- CSR build ----------------
__global__ __launch_bounds__(256) void hist_kernel(const int* __restrict__ ei,
                                                   int* __restrict__ count) {
    for (int e = blockIdx.x * blockDim.x + threadIdx.x; e < N_EDGES;
         e += gridDim.x * blockDim.x)
        atomicAdd(&count[ei[N_EDGES + e]], 1);
}

__global__ __launch_bounds__(SCAN_B) void scan_partial_kernel(const int* __restrict__ count,
                                                              int* __restrict__ rowptr,
                                                              int* __restrict__ blockSum) {
    __shared__ int buf[SCAN_B];
    const int b = blockIdx.x, tid = threadIdx.x;
    const int i = b * SCAN_B + tid;
    int v = (i < N_NODES) ? count[i] : 0;
    buf[tid] = v;
    __syncthreads();
    for (int off = 1; off < SCAN_B; off <<= 1) {
        int t = (tid >= off) ? buf[tid - off] : 0;
        __syncthreads();
        buf[tid] += t;
        __syncthreads();
    }
    if (i < N_NODES) rowptr[i] = buf[tid] - v;      // exclusive within block
    if (tid == SCAN_B - 1) blockSum[b] = buf[tid];
}

__global__ void scan_tops_kernel(int* __restrict__ blockSum, int* __restrict__ rowptrN) {
    const int lane = threadIdx.x;                    // 64 threads = 1 wave
    int v = (lane < SCAN_NB) ? blockSum[lane] : 0;
    int s = v;
    for (int off = 1; off < 64; off <<= 1) {
        int t = __shfl_up(s, off);
        if (lane >= off) s += t;
    }
    if (lane < SCAN_NB) blockSum[lane] = s - v;      // exclusive block offsets
    if (lane == 63) rowptrN[0] = s;                  // total -> rowptr[N_NODES]
}

__global__ __launch_bounds__(SCAN_B) void scan_add_kernel(const int* __restrict__ blockSum,
                                                          int* __restrict__ rowptr,
                                                          int* __restrict__ cursor) {
    const int i = blockIdx.x * SCAN_B + threadIdx.x;
    if (i < N_NODES) {
        int r = rowptr[i] + blockSum[blockIdx.x];
        rowptr[i] = r;
        cursor[i] = r;
    }
}

__global__ __launch_bounds__(256) void scatter_kernel(const int* __restrict__ ei,
                                                      int* __restrict__ cursor,
                                                      int2* __restrict__ pairsSD,
                                                      int* __restrict__ eid) {
    for (int e = blockIdx.x * blockDim.x + threadIdx.x; e < N_EDGES;
         e += gridDim.x * blockDim.x) {
        int s = ei[e];
        int d = ei[N_EDGES + e];
        int pos = atomicAdd(&cursor[d], 1);
        pairsSD[pos] = make_int2(s, d);
        eid[pos] = e;
    }
}

__global__ __launch_bounds__(256) void permute_kernel(const float4* __restrict__ ea4,
                                                      const int* __restrict__ eid,
                                                      float4* __restrict__ eaP) {
    int t = blockIdx.x * blockDim.x + threadIdx.x;
    if (t < N_EDGES * 4) {
        int j = t >> 2, c = t & 3;
        eaP[t] = ea4[((size_t)eid[j] << 2) + c];
    }
}

// ---------------- fuse readout weights ----------------
__global__ void fuse_weights_kernel(
    const float* __restrict__ W1, const float* __restrict__ b1,
    const float* __restrict__ W2, const float* __restrict__ b2,
    float* __restrict__ Wf, float* __restrict__ bf) {
    const int t = threadIdx.x;     // 128 threads
    const int i = t >> 1;
    const int j = t & 1;
    float acc = 0.f;
    for (int k = 0; k < 128; ++k) acc += W1[i * 128 + k] * W2[k * 2 + j];
    Wf[i * 2 + j] = acc;
    if (i == 0) {
        float accb = b2[j];
        for (int k = 0; k < 128; ++k) accb += b1[k] * W2[k * 2 + j];
        bf[j] = accb;
    }
}

// ---------------- fused GINE layer: lane-per-edge, float4 chunks, LDS tile ----------------
#define EPSTEP(Q, C, K) \
    p.x = fmaf(Q.C, wq[K].x, p.x); p.y = fmaf(Q.C, wq[K].y, p.y); \
    p.z = fmaf(Q.C, wq[K].z, p.z); p.w = fmaf(Q.C, wq[K].w, p.w);

template <bool LAST>
__global__ __launch_bounds__(TPB, 4) void conv_kernel(
    const float* __restrict__ h,
    const int* __restrict__ rowptr,
    const int2* __restrict__ pairsSD,
    const int* __restrict__ eid,
    const float* __restrict__ eaSrc, const int usePerm,
    const float* __restrict__ We, const float* __restrict__ be,
    const float* __restrict__ Wn, const float* __restrict__ bn,
    const float* __restrict__ Wf, const float* __restrict__ bf,
    float* __restrict__ hout, float* __restrict__ out)
{
    __shared__ float aggrS[NPB * F];   // 16 KB, chunk-slot XOR-swizzled per node
    const int tid  = threadIdx.x;
    const int lane = tid & 63;
    const int wid  = tid >> 6;
    const int n0   = blockIdx.x * NPB;
    const int nCnt = min(NPB, N_NODES - n0);

    for (int i = tid; i < NPB * F; i += TPB) aggrS[i] = 0.f;
    __syncthreads();

    const int eBeg = rowptr[n0];
    const int eEnd = rowptr[n0 + nCnt];

    // ---- edge phase: wave w does chunks {w, w+4, w+8, w+12}; lane = edge ----
    for (int ci = 0; ci < 4; ++ci) {
        const int c = ci * NWAVE + wid;              // 0..15
        float4 wq[EDIM];
#pragma unroll
        for (int k = 0; k < EDIM; ++k) wq[k] = *(const float4*)&We[k * F + c * 4];
        const float4 be4 = *(const float4*)&be[c * 4];

        if (eBeg < eEnd) {
            int2 sd = pairsSD[min(eBeg + lane, eEnd - 1)];   // preload group 0 pairs
#pragma unroll 1
            for (int j0 = eBeg; j0 < eEnd; j0 += 64) {
                const int j = j0 + lane;
                const int jj = (j < eEnd) ? j : (eEnd - 1);
                // prefetch next group's pairs early (breaks pairs->h chain)
                const int j0n = j0 + 64;
                int2 sdN = (j0n < eEnd) ? pairsSD[min(j0n + lane, eEnd - 1)]
                                        : make_int2(0, n0);
                const float4* ep = (const float4*)eaSrc +
                                   ((size_t)(usePerm ? jj : eid[jj]) << 2);
                float4 q0 = ep[0], q1 = ep[1], q2 = ep[2], q3 = ep[3];
                float4 h4 = *(const float4*)&h[((size_t)sd.x << 6) + c * 4];  // 64 scattered 16B gathers
                float4 p = be4;
                EPSTEP(q0, x, 0)  EPSTEP(q0, y, 1)  EPSTEP(q0, z, 2)  EPSTEP(q0, w, 3)
                EPSTEP(q1, x, 4)  EPSTEP(q1, y, 5)  EPSTEP(q1, z, 6)  EPSTEP(q1, w, 7)
                EPSTEP(q2, x, 8)  EPSTEP(q2, y, 9)  EPSTEP(q2, z, 10) EPSTEP(q2, w, 11)
                EPSTEP(q3, x, 12) EPSTEP(q3, y, 13) EPSTEP(q3, z, 14) EPSTEP(q3, w, 15)
                float4 m;
                m.x = fmaxf(h4.x + p.x, 0.f);
                m.y = fmaxf(h4.y + p.y, 0.f);
                m.z = fmaxf(h4.z + p.z, 0.f);
                m.w = fmaxf(h4.w + p.w, 0.f);
                if (j >= eEnd) { m.x = 0.f; m.y = 0.f; m.z = 0.f; m.w = 0.f; }
                const int nl = sd.y - n0;
                const int slot = c ^ (nl & 15);
                float* ap = &aggrS[(nl << 6) + (slot << 2)];
                atomicAdd(ap + 0, m.x);
                atomicAdd(ap + 1, m.y);
                atomicAdd(ap + 2, m.z);
                atomicAdd(ap + 3, m.w);
                sd = sdN;
            }
        }
    }
    __syncthreads();

    // ---- t = h + aggr (swizzle-aware, conflict-free) ----
    {
        const int cl_ = lane >> 2, il = lane & 3;
        for (int nl = wid; nl < nCnt; nl += NWAVE) {
            const int slot = cl_ ^ (nl & 15);
            aggrS[(nl << 6) + (slot << 2) + il] += h[((size_t)(n0 + nl) << 6) + lane];
        }
    }
    __syncthreads();

    // ---- node GEMM: 16 nodes/wave; Wn coalesced loads; t via uniform b128 broadcasts ----
    const int nlBase = wid * NPW;   // multiple of 16 -> (nlBase+i)&15 == i
    float accv[NPW];
    const float bnR = bn[lane];
#pragma unroll
    for (int i = 0; i < NPW; ++i) accv[i] = bnR;
#pragma unroll
    for (int q = 0; q < 16; ++q) {
        const float w0 = Wn[(4 * q + 0) * F + lane];
        const float w1 = Wn[(4 * q + 1) * F + lane];
        const float w2 = Wn[(4 * q + 2) * F + lane];
        const float w3 = Wn[(4 * q + 3) * F + lane];
#pragma unroll
        for (int i = 0; i < NPW; ++i) {
            const int slot = q ^ i;
            const float4 t4 = *(const float4*)&aggrS[((nlBase + i) << 6) + (slot << 2)];
            accv[i] = fmaf(t4.w, w3, fmaf(t4.z, w2, fmaf(t4.y, w1, fmaf(t4.x, w0, accv[i]))));
        }
    }
    float wf0 = 0.f, wf1 = 0.f, bf0 = 0.f, bf1 = 0.f;
    if (LAST) { wf0 = Wf[lane * 2]; wf1 = Wf[lane * 2 + 1]; bf0 = bf[0]; bf1 = bf[1]; }
#pragma unroll
    for (int i = 0; i < NPW; ++i) {
        const int nl = nlBase + i;
        if (nl >= nCnt) break;
        float acc = accv[i];
        acc = acc >= 0.f ? acc : NEG_SLOPE * acc;            // LeakyReLU
        if (!LAST) {
            hout[((size_t)(n0 + nl) << 6) + lane] = acc;
        } else {
            float v0 = acc * wf0, v1 = acc * wf1;
#pragma unroll
            for (int off = 32; off; off >>= 1) {
                v0 += __shfl_down(v0, off);
                v1 += __shfl_down(v1, off);
            }
            if (lane == 0) {
                out[(n0 + nl) * 2 + 0] = v0 + bf0;
                out[(n0 + nl) * 2 + 1] = v1 + bf1;
            }
        }
    }
}

extern "C" void kernel_launch(void* const* d_in, const int* in_sizes, int n_in,
                              void* d_out, int out_size, void* d_ws, size_t ws_size,
                              hipStream_t stream) {
    const float* x  = (const float*)d_in[0];
    const int*   ei = (const int*)d_in[1];
    const float* ea = (const float*)d_in[2];
    const float* Wn = (const float*)d_in[3];
    const float* bn = (const float*)d_in[4];
    const float* We = (const float*)d_in[5];     // [3,16,64]
    const float* be = (const float*)d_in[6];     // [3,64]
    const float* W1 = (const float*)d_in[7];
    const float* b1 = (const float*)d_in[8];
    const float* W2 = (const float*)d_in[9];
    const float* b2 = (const float*)d_in[10];
    float* out = (float*)d_out;

    size_t off = 0;
    char* base = (char*)d_ws;
    auto alloc = [&](size_t bytes) {
        off = (off + 15) & ~(size_t)15;
        char* p = base + off;
        off += bytes;
        return p;
    };
    int*   count    = (int*)alloc(sizeof(int) * N_NODES);
    int*   rowptr   = (int*)alloc(sizeof(int) * (N_NODES + 1));
    int*   cursor   = (int*)alloc(sizeof(int) * N_NODES);
    int*   blockSum = (int*)alloc(sizeof(int) * SCAN_NB);
    int2*  pairsSD  = (int2*)alloc(sizeof(int2) * N_EDGES);
    int*   eid      = (int*)alloc(sizeof(int) * N_EDGES);
    float* hA       = (float*)alloc(sizeof(float) * (size_t)N_NODES * F);
    float* hB       = (float*)alloc(sizeof(float) * (size_t)N_NODES * F);
    float* Wf       = (float*)alloc(sizeof(float) * F * 2);
    float* bf       = (float*)alloc(sizeof(float) * 2);
    float* eaP      = (float*)alloc(sizeof(float) * (size_t)N_EDGES * EDIM);
    const int usePerm = (ws_size >= off) ? 1 : 0;

    fuse_weights_kernel<<<1, 128, 0, stream>>>(W1, b1, W2, b2, Wf, bf);

    // CSR build (edge_index is layer-invariant)
    hipMemsetAsync(count, 0, sizeof(int) * N_NODES, stream);
    hist_kernel<<<1024, 256, 0, stream>>>(ei, count);
    scan_partial_kernel<<<SCAN_NB, SCAN_B, 0, stream>>>(count, rowptr, blockSum);
    scan_tops_kernel<<<1, 64, 0, stream>>>(blockSum, rowptr + N_NODES);
    scan_add_kernel<<<SCAN_NB, SCAN_B, 0, stream>>>(blockSum, rowptr, cursor);
    scatter_kernel<<<1024, 256, 0, stream>>>(ei, cursor, pairsSD, eid);
    if (usePerm)
        permute_kernel<<<(N_EDGES * 4 + 255) / 256, 256, 0, stream>>>(
            (const float4*)ea, eid, (float4*)eaP);

    const float* eaSrc = usePerm ? eaP : ea;
    conv_kernel<false><<<NBLK, TPB, 0, stream>>>(x, rowptr, pairsSD, eid, eaSrc, usePerm,
        We + 0 * EDIM * F, be + 0 * F, Wn, bn, Wf, bf, hA, out);
    conv_kernel<false><<<NBLK, TPB, 0, stream>>>(hA, rowptr, pairsSD, eid, eaSrc, usePerm,
        We + 1 * EDIM * F, be + 1 * F, Wn, bn, Wf, bf, hB, out);
    conv_kernel<true><<<NBLK, TPB, 0, stream>>>(hB, rowptr, pairsSD, eid, eaSrc, usePerm,
        We + 2 * EDIM * F, be + 2 * F, Wn, bn, Wf, bf, nullptr, out);
}